// Round 16
// baseline (265.608 us; speedup 1.0000x reference)
//
#include <hip/hip_runtime.h>
#include <hip/hip_bf16.h>
#include <cstdint>

#define BN_SCALEF 0.99999500003749975f  // 1/sqrt(1+1e-5)
#define EXP_SHIFT 4.0f

// Problem constants: B=128, N=200, F=768, H=8, Fo=32, Fh=256

typedef _Float16 half8 __attribute__((ext_vector_type(8)));
typedef _Float16 half4 __attribute__((ext_vector_type(4)));
typedef float floatx4 __attribute__((ext_vector_type(4)));

// ---------------------------------------------------------------- prep: pack_mask + Wcat^T + W2t48
// R5 mask/transpose parts (proven); W2t48 tail fixed in isolation: Wq staged
// to LDS coalesced so the 32-iter serial loop reads LDS, not strided global.

__global__ __launch_bounds__(256) void prep(const int* __restrict__ adj,
                                            const float* __restrict__ W_heads,
                                            const float* __restrict__ Ws_in,
                                            const float* __restrict__ Wp_in,
                                            const float* __restrict__ Wq_in,
                                            const float* __restrict__ a_sent,
                                            const float* __restrict__ a_para,
                                            const float* __restrict__ a_q,
                                            unsigned int* __restrict__ maskw,
                                            _Float16* __restrict__ Bt,
                                            _Float16* __restrict__ W2t48) {
    int blk = blockIdx.x;
    int t = threadIdx.x;
    if (blk < 1600) {
        int w = t >> 6, lane = t & 63;
        for (int task = w; task < 64; task += 4) {
            int r = blk * 16 + (task >> 2);
            int c0 = (task & 3) * 64;
            int j = c0 + lane;
            bool v = (j < 200) && (adj[(size_t)r * 200 + j] > 0);
            unsigned long long m = __ballot(v ? 1 : 0);
            if (lane == 0) {
                maskw[r * 8 + (c0 >> 5)]     = (unsigned int)(m & 0xffffffffULL);
                maskw[r * 8 + (c0 >> 5) + 1] = (unsigned int)(m >> 32);
            }
        }
    } else if (blk < 1792) {
        __shared__ float ld[32][36];
        int blk2 = blk - 1600;          // h = blk2/24, f-tile = blk2%24
        int h = blk2 / 24, f0 = (blk2 % 24) * 32;
        int idx = t * 4;
        int fr = idx >> 5, o0 = idx & 31;
        float4 v = *(const float4*)&W_heads[(size_t)h * 24576 + (size_t)(f0 + fr) * 32 + o0];
        ld[fr][o0] = v.x; ld[fr][o0 + 1] = v.y; ld[fr][o0 + 2] = v.z; ld[fr][o0 + 3] = v.w;
        __syncthreads();
        int o = idx >> 5, fr0 = idx & 31;
        half4 hv;
#pragma unroll
        for (int u = 0; u < 4; ++u) hv[u] = (_Float16)ld[fr0 + u][o];
        *(half4*)&Bt[(size_t)(h * 32 + o) * 768 + f0 + fr0] = hv;
    } else {
        __shared__ float WqL[32 * 257];   // [o][k], pad 1 -> conflict-free both phases
        for (int i = t; i < 8192; i += 256) {
            int kk = i >> 5, oo = i & 31;
            WqL[oo * 257 + kk] = Wq_in[i];     // coalesced read, independent iters
        }
        __syncthreads();
        int k = t;  // 256
        float w0 = Ws_in[k * 2], w1 = Ws_in[k * 2 + 1];
        float p0 = Wp_in[k * 2], p1 = Wp_in[k * 2 + 1];
        W2t48[0 * 256 + k] = (_Float16)w0;
        W2t48[1 * 256 + k] = (_Float16)w1;
        W2t48[2 * 256 + k] = (_Float16)p0;
        W2t48[3 * 256 + k] = (_Float16)p1;
#pragma unroll
        for (int c = 4; c < 36; ++c)
            W2t48[c * 256 + k] = (_Float16)WqL[(c - 4) * 257 + k];
        W2t48[36 * 256 + k] = (_Float16)(w0 * a_sent[0] + w1 * a_sent[1]);
        W2t48[37 * 256 + k] = (_Float16)(w0 * a_sent[2] + w1 * a_sent[3]);
        W2t48[38 * 256 + k] = (_Float16)(p0 * a_para[0] + p1 * a_para[1]);
        W2t48[39 * 256 + k] = (_Float16)(p0 * a_para[2] + p1 * a_para[3]);
        float q1 = 0.f, q2 = 0.f;
#pragma unroll
        for (int o = 0; o < 32; ++o) {
            float wv = WqL[o * 257 + k];
            q1 += wv * a_q[o];
            q2 += wv * a_q[32 + o];
        }
        W2t48[40 * 256 + k] = (_Float16)q1;
        W2t48[41 * 256 + k] = (_Float16)q2;
        for (int c = 42; c < 48; ++c) W2t48[c * 256 + k] = (_Float16)0.f;
    }
}

// ---------------------------------------------------------------- GEMM1 v8 (proven 52-53.7): v6 skeleton + dist-2 register prefetch

__global__ __launch_bounds__(512) void gemm1_mfma(const float* __restrict__ A,
                                                  const _Float16* __restrict__ Bt,
                                                  _Float16* __restrict__ h16) {
    __shared__ __align__(16) _Float16 As[128 * 40];   // [row][k], pad 8
    __shared__ __align__(16) _Float16 Bs[256 * 40];   // [col][k]
    int t = threadIdx.x;
    int m0 = blockIdx.x * 128;      // 200 blocks
    int w = t >> 6, lane = t & 63;
    int wr = w >> 2, wc = w & 3;    // 2x4 wave grid; wave tile 64 rows x 64 cols
    int quad = lane >> 4, l16 = lane & 15;

    floatx4 acc[4][4];
#pragma unroll
    for (int i = 0; i < 4; ++i)
#pragma unroll
        for (int j = 0; j < 4; ++j) acc[i][j] = (floatx4){0.f, 0.f, 0.f, 0.f};

    int arow = t >> 2, ako = (t & 3) * 8;      // A: 128 rows x 32 k, two float4/thread
    int bcol = t >> 1, bko = (t & 1) * 16;     // B: 256 cols x 32 k, two uint4/thread
    const float*    Aptr = &A[(size_t)(m0 + arow) * 768 + ako];
    const _Float16* Bptr = &Bt[(size_t)bcol * 768 + bko];

    // regset X holds tiles 0,2,4,.. ; regset Y holds tiles 1,3,5,..
    float4 xa0 = *(const float4*)(Aptr);
    float4 xa1 = *(const float4*)(Aptr + 4);
    uint4  xb0 = *(const uint4*)(Bptr);
    uint4  xb1 = *(const uint4*)(Bptr + 8);
    float4 ya0 = *(const float4*)(Aptr + 32);
    float4 ya1 = *(const float4*)(Aptr + 36);
    uint4  yb0 = *(const uint4*)(Bptr + 32);
    uint4  yb1 = *(const uint4*)(Bptr + 40);

#define GEMM1_BODY(PA0, PA1, PB0, PB1, KNEXT)                                  \
    {                                                                          \
        half4 ah;                                                              \
        ah[0] = (_Float16)PA0.x; ah[1] = (_Float16)PA0.y;                      \
        ah[2] = (_Float16)PA0.z; ah[3] = (_Float16)PA0.w;                      \
        *(half4*)&As[arow * 40 + ako] = ah;                                    \
        ah[0] = (_Float16)PA1.x; ah[1] = (_Float16)PA1.y;                      \
        ah[2] = (_Float16)PA1.z; ah[3] = (_Float16)PA1.w;                      \
        *(half4*)&As[arow * 40 + ako + 4] = ah;                                \
        *(uint4*)&Bs[bcol * 40 + bko]     = PB0;                               \
        *(uint4*)&Bs[bcol * 40 + bko + 8] = PB1;                               \
        __syncthreads();                                                       \
        if ((KNEXT) < 768) {                                                   \
            PA0 = *(const float4*)(Aptr + (KNEXT));                            \
            PA1 = *(const float4*)(Aptr + (KNEXT) + 4);                        \
            PB0 = *(const uint4*)(Bptr + (KNEXT));                             \
            PB1 = *(const uint4*)(Bptr + (KNEXT) + 8);                         \
        }                                                                      \
        half8 af[4], bf[4];                                                    \
        _Pragma("unroll")                                                      \
        for (int rt = 0; rt < 4; ++rt)                                         \
            af[rt] = *(half8*)&As[(wr * 64 + rt * 16 + l16) * 40 + quad * 8];  \
        _Pragma("unroll")                                                      \
        for (int ct = 0; ct < 4; ++ct)                                         \
            bf[ct] = *(half8*)&Bs[(wc * 64 + ct * 16 + l16) * 40 + quad * 8];  \
        _Pragma("unroll")                                                      \
        for (int rt = 0; rt < 4; ++rt)                                         \
            _Pragma("unroll")                                                  \
            for (int ct = 0; ct < 4; ++ct)                                     \
                acc[rt][ct] = __builtin_amdgcn_mfma_f32_16x16x32_f16(af[rt], bf[ct], acc[rt][ct], 0, 0, 0); \
        __syncthreads();                                                       \
    }

    for (int k0 = 0; k0 < 768; k0 += 64) {
        GEMM1_BODY(xa0, xa1, xb0, xb1, k0 + 64)     // tile k0   (dist-2: loads k0+64)
        GEMM1_BODY(ya0, ya1, yb0, yb1, k0 + 96)     // tile k0+32 (dist-2: loads k0+96)
    }
#undef GEMM1_BODY

    int rbase = m0 + wr * 64;
    int cbase = wc * 64;
#pragma unroll
    for (int rt = 0; rt < 4; ++rt)
#pragma unroll
        for (int ct = 0; ct < 4; ++ct) {
            int gc = cbase + ct * 16 + l16;
#pragma unroll
            for (int r = 0; r < 4; ++r) {
                int gr = rbase + rt * 16 + quad * 4 + r;
                h16[(size_t)gr * 256 + gc] = (_Float16)acc[rt][ct][r];
            }
        }
}

// ---------------------------------------------------------------- head attention v4 (R8/R13 proven, unsplit)

__global__ __launch_bounds__(256) void attn_heads_mfma(
    const _Float16* __restrict__ h16,
    const float* __restrict__ a_h,
    const unsigned int* __restrict__ maskw,
    const float* __restrict__ bnh_g, const float* __restrict__ bnh_b,
    const float* __restrict__ bnt_g, const float* __restrict__ bnt_b,
    _Float16* __restrict__ x16h) {
    __shared__ __align__(16) _Float16 Bs[32 * 228];   // h^T rows 0..31
    __shared__ __align__(16) _Float16 Bs2[16 * 228];  // row 0 = ones; bytes 512.. = Ms
    __shared__ float s1s[256], s2s[256];
    unsigned int* Ms = (unsigned int*)((char*)Bs2 + 512);   // 200 rows x 8 words = 6400 B
    int hb = blockIdx.x;
    int h = hb >> 7, b = hb & 127;
    int t = threadIdx.x;

    // ---- prologue (single barrier): s1/s2 from global, Bs stage+tail-zero,
    //      Bs2 row 0, mask table
    if (t < 200) {
        const _Float16* hp = &h16[(size_t)(b * 200 + t) * 256 + h * 32];
        half8 v0 = *(const half8*)(hp);
        half8 v1 = *(const half8*)(hp + 8);
        half8 v2 = *(const half8*)(hp + 16);
        half8 v3 = *(const half8*)(hp + 24);
        const float* ab = &a_h[h * 64];
        float acc1 = 0.f, acc2 = 0.f;
#pragma unroll
        for (int o = 0; o < 8; ++o) {
            acc1 += (float)v0[o] * ab[o]      + (float)v1[o] * ab[8 + o]
                  + (float)v2[o] * ab[16 + o] + (float)v3[o] * ab[24 + o];
            acc2 += (float)v0[o] * ab[32 + o] + (float)v1[o] * ab[40 + o]
                  + (float)v2[o] * ab[48 + o] + (float)v3[o] * ab[56 + o];
        }
        s1s[t] = acc1; s2s[t] = acc2;
    } else {
        s1s[t] = 0.f; s2s[t] = 0.f;
    }
    for (int idx = t; idx < 800; idx += 256) {
        int j = idx >> 2, w8 = (idx & 3) * 8;
        half8 v = *(const half8*)&h16[(size_t)(b * 200 + j) * 256 + h * 32 + w8];
#pragma unroll
        for (int u = 0; u < 8; ++u) Bs[(w8 + u) * 228 + j] = v[u];
    }
    if (t < 224) {   // zero Bs cols 200..227, rows 0..27
        int zr = t >> 3, zc = (t & 7) * 4;
        if (zc < 28) {
            half4 z = {(_Float16)0.f, (_Float16)0.f, (_Float16)0.f, (_Float16)0.f};
            *(half4*)&Bs[zr * 228 + 200 + zc] = z;
        }
    }
    if (t >= 224 && t < 256) {   // rows 28..31
        int zr = 28 + ((t - 224) >> 3), zc = ((t - 224) & 7) * 4;
        if (zc < 28) {
            half4 z = {(_Float16)0.f, (_Float16)0.f, (_Float16)0.f, (_Float16)0.f};
            *(half4*)&Bs[zr * 228 + 200 + zc] = z;
        }
    }
    if (t < 228) Bs2[t] = (t < 200) ? (_Float16)1.0f : (_Float16)0.f;
    for (int idx = t; idx < 400; idx += 256)
        *(uint4*)&Ms[idx * 4] = *(const uint4*)&maskw[(size_t)b * 1600 + idx * 4];
    __syncthreads();

    int w = t >> 6, lane = t & 63;
    int l16 = lane & 15, quad = lane >> 4;

    for (int tile = w; tile < 13; tile += 4) {
        int i_base = tile * 16;
        int i = i_base + l16;                 // this lane's P row (may be >=200: masked later)
        float s1v = s1s[i];
        half8 pa[7];
#pragma unroll
        for (int kt = 0; kt < 7; ++kt) {
            unsigned int mw = Ms[i * 8 + kt];
            unsigned int bits = (mw >> (quad * 8)) & 0xffu;
            const float* s2p = &s2s[kt * 32 + quad * 8];
            float4 sa = *(const float4*)s2p;
            float4 sb = *(const float4*)(s2p + 4);
            half8 pv;
#pragma unroll
            for (int u = 0; u < 8; ++u) {
                float s2v = (u < 4) ? ((const float*)&sa)[u] : ((const float*)&sb)[u - 4];
                float e = s1v + s2v;
                e = fmaxf(e, 0.3f * e);
                float p = ((bits >> u) & 1u) ? __expf(e - EXP_SHIFT) : 0.f;
                pv[u] = (_Float16)p;
            }
            pa[kt] = pv;
        }
        floatx4 acc0 = {0.f, 0.f, 0.f, 0.f};
        floatx4 acc1 = {0.f, 0.f, 0.f, 0.f};
        floatx4 acc2 = {0.f, 0.f, 0.f, 0.f};
#pragma unroll
        for (int kt = 0; kt < 7; ++kt) {
            half8 b0 = *(half8*)&Bs[(l16) * 228 + kt * 32 + quad * 8];
            half8 b1 = *(half8*)&Bs[(16 + l16) * 228 + kt * 32 + quad * 8];
            half8 b2 = *(half8*)&Bs2[(l16) * 228 + kt * 32 + quad * 8];
            acc0 = __builtin_amdgcn_mfma_f32_16x16x32_f16(pa[kt], b0, acc0, 0, 0, 0);
            acc1 = __builtin_amdgcn_mfma_f32_16x16x32_f16(pa[kt], b1, acc1, 0, 0, 0);
            acc2 = __builtin_amdgcn_mfma_f32_16x16x32_f16(pa[kt], b2, acc2, 0, 0, 0);
        }
#pragma unroll
        for (int r = 0; r < 4; ++r) {
            int io = i_base + quad * 4 + r;
            float rsum = __shfl(acc2[r], (lane & 48), 64);
            if (io < 200) {
                float inv = 1.f / rsum;
                float g1 = BN_SCALEF * bnh_g[h * 200 + io], c1 = bnh_b[h * 200 + io];
                float g2 = BN_SCALEF * bnt_g[io], c2 = bnt_b[io];
                float v0 = acc0[r] * inv * g1 + c1;
                v0 = v0 > 0.f ? v0 : __expf(v0) - 1.f;
                v0 = v0 * g2 + c2;
                float v1 = acc1[r] * inv * g1 + c1;
                v1 = v1 > 0.f ? v1 : __expf(v1) - 1.f;
                v1 = v1 * g2 + c2;
                size_t base = (size_t)h * 819200 + (size_t)(b * 200 + io) * 32;
                x16h[base + l16]      = (_Float16)v0;
                x16h[base + 16 + l16] = (_Float16)v1;
            }
        }
    }
}

// ---------------------------------------------------------------- GEMM2 via MFMA: H2p[25600][48] = x16h @ W2t48^T

__global__ __launch_bounds__(256) void gemm2m(const _Float16* __restrict__ Xh,
                                              const _Float16* __restrict__ Wt,
                                              float* __restrict__ H2p) {
    __shared__ __align__(16) _Float16 Xs[64 * 264];   // [row][k = h*32+o], pad 8
    __shared__ __align__(16) _Float16 Ws[48 * 264];
    int t = threadIdx.x;
    int m0 = blockIdx.x * 64;       // 400 blocks
    int srow = t >> 2, schunk = (t & 3) * 8;
#pragma unroll
    for (int h = 0; h < 8; ++h) {
        half8 v = *(const half8*)&Xh[(size_t)h * 819200 + (size_t)(m0 + srow) * 32 + schunk];
        *(half8*)&Xs[srow * 264 + h * 32 + schunk] = v;
    }
#pragma unroll
    for (int p = 0; p < 6; ++p) {
        int g = t + 256 * p;                 // 1536 half8 chunks
        int n = g >> 5, ko = (g & 31) * 8;
        *(half8*)&Ws[n * 264 + ko] = *(const half8*)&Wt[(size_t)n * 256 + ko];
    }
    __syncthreads();

    int w = t >> 6, lane = t & 63;
    int l16 = lane & 15, quad = lane >> 4;
    int rbase = w * 16;
    floatx4 acc[3];
#pragma unroll
    for (int c = 0; c < 3; ++c) acc[c] = (floatx4){0.f, 0.f, 0.f, 0.f};
#pragma unroll
    for (int kt = 0; kt < 8; ++kt) {
        half8 af = *(half8*)&Xs[(rbase + l16) * 264 + kt * 32 + quad * 8];
#pragma unroll
        for (int ct = 0; ct < 3; ++ct) {
            half8 bf = *(half8*)&Ws[(ct * 16 + l16) * 264 + kt * 32 + quad * 8];
            acc[ct] = __builtin_amdgcn_mfma_f32_16x16x32_f16(af, bf, acc[ct], 0, 0, 0);
        }
    }
#pragma unroll
    for (int ct = 0; ct < 3; ++ct) {
        int col = ct * 16 + l16;
#pragma unroll
        for (int r = 0; r < 4; ++r) {
            int row = m0 + rbase + quad * 4 + r;
            H2p[(size_t)row * 48 + col] = acc[ct][r];
        }
    }
}

// ---------------------------------------------------------------- sent+para+q attention v3 (R13 proven): 4 row-chunks of 50 + q

__global__ __launch_bounds__(256) void attn_spq(const float* __restrict__ H2p,
                                                const unsigned int* __restrict__ maskw,
                                                const float* __restrict__ bns_g, const float* __restrict__ bns_b,
                                                const float* __restrict__ bnp_g, const float* __restrict__ bnp_b,
                                                const float* __restrict__ bnq_g, const float* __restrict__ bnq_b,
                                                const float* __restrict__ W2, float* __restrict__ out) {
    int b = blockIdx.x;
    int t = threadIdx.x;
    if (blockIdx.y == 4) {
        __shared__ float p_lds[200];
        __shared__ float redd[4];
        __shared__ float red2[256];
        float s1v = H2p[(size_t)(b * 200) * 48 + 40];
        float p = 0.f;
        if (t < 200) {
            unsigned int mw = maskw[(size_t)(b * 200) * 8 + (t >> 5)];
            if ((mw >> (t & 31)) & 1u) {
                float x = s1v + H2p[(size_t)(b * 200 + t) * 48 + 41];
                x = fmaxf(x, 0.3f * x);
                p = __expf(x - EXP_SHIFT);
            }
            p_lds[t] = p;
        }
        float ds = p;
        for (int off = 32; off; off >>= 1) ds += __shfl_xor(ds, off, 64);
        if ((t & 63) == 0) redd[t >> 6] = ds;
        __syncthreads();
        ds = redd[0] + redd[1] + redd[2] + redd[3];
        int o = t & 31, g = t >> 5;
        float acc = 0.f;
        for (int j = g; j < 200; j += 8)
            acc += p_lds[j] * H2p[(size_t)(b * 200 + j) * 48 + 4 + o];
        red2[t] = acc;
        __syncthreads();
        if (t < 32) {
            float s = 0.f;
#pragma unroll
            for (int gg = 0; gg < 8; ++gg) s += red2[gg * 32 + t];
            float qv = (s / ds) * (BN_SCALEF * bnq_g[0]) + bnq_b[0];
            float c0 = qv * W2[t * 2], c1 = qv * W2[t * 2 + 1];
#pragma unroll
            for (int off = 16; off; off >>= 1) {
                c0 += __shfl_xor(c0, off, 64);
                c1 += __shfl_xor(c1, off, 64);
            }
            if (t == 0) {
                out[102400 + b * 2 + 0] = c0 > 0.f ? c0 : __expf(c0) - 1.f;
                out[102400 + b * 2 + 1] = c1 > 0.f ? c1 : __expf(c1) - 1.f;
            }
        }
        return;
    }
    __shared__ float s2s[200], s2p[200];
    __shared__ float s1sA[200], s1pA[200];
    __shared__ __align__(16) float hsp[200 * 4];
    __shared__ __align__(16) unsigned int Msq[400];   // 50 rows x 8 mask words
    int chunk = blockIdx.y;                            // 0..3, rows [chunk*50, chunk*50+50)
    if (t < 200) {
        const float* hr = &H2p[(size_t)(b * 200 + t) * 48];
        float4 hv = *(const float4*)hr;
        *(float4*)&hsp[t * 4] = hv;
        s1sA[t] = hr[36]; s2s[t] = hr[37];
        s1pA[t] = hr[38]; s2p[t] = hr[39];
    }
    for (int idx = t; idx < 100; idx += 256)
        *(uint4*)&Msq[idx * 4] = *(const uint4*)&maskw[((size_t)(b * 200) + chunk * 50) * 8 + idx * 4];
    __syncthreads();
    int w = t >> 6, lane = t & 63;
    for (int it = 0; it < 13; ++it) {
        int lr = it * 4 + w;                 // local row in chunk
        if (lr >= 50) break;
        int i = chunk * 50 + lr;
        float s1sv = s1sA[i];
        float s1pv = s1pA[i];
        float ds = 0.f, dp = 0.f, pa0 = 0.f, pa1 = 0.f, pb0 = 0.f, pb1 = 0.f;
#pragma unroll
        for (int q = 0; q < 4; ++q) {
            int j = lane + 64 * q;
            if (j < 200) {
                unsigned int mw = Msq[lr * 8 + (j >> 5)];
                if ((mw >> (j & 31)) & 1u) {
                    float x1 = s1sv + s2s[j]; x1 = fmaxf(x1, 0.3f * x1);
                    float x2 = s1pv + s2p[j]; x2 = fmaxf(x2, 0.3f * x2);
                    float p1 = __expf(x1 - EXP_SHIFT), p2 = __expf(x2 - EXP_SHIFT);
                    ds += p1; dp += p2;
                    float4 hv = *(float4*)&hsp[j * 4];
                    pa0 += p1 * hv.x; pa1 += p1 * hv.y;
                    pb0 += p2 * hv.z; pb1 += p2 * hv.w;
                }
            }
        }
        for (int off = 32; off; off >>= 1) {
            ds  += __shfl_xor(ds, off, 64);  dp  += __shfl_xor(dp, off, 64);
            pa0 += __shfl_xor(pa0, off, 64); pa1 += __shfl_xor(pa1, off, 64);
            pb0 += __shfl_xor(pb0, off, 64); pb1 += __shfl_xor(pb1, off, 64);
        }
        if (lane == 0) {
            float gs = BN_SCALEF * bns_g[i], bs = bns_b[i];
            float v0 = (pa0 / ds) * gs + bs, v1 = (pa1 / ds) * gs + bs;
            out[(size_t)(b * 200 + i) * 2 + 0] = 1.f / (1.f + __expf(-v0));
            out[(size_t)(b * 200 + i) * 2 + 1] = 1.f / (1.f + __expf(-v1));
            float gp = BN_SCALEF * bnp_g[i], bp = bnp_b[i];
            float u0 = (pb0 / dp) * gp + bp, u1 = (pb1 / dp) * gp + bp;
            out[51200 + (size_t)(b * 200 + i) * 2 + 0] = u0 > 0.f ? u0 : __expf(u0) - 1.f;
            out[51200 + (size_t)(b * 200 + i) * 2 + 1] = u1 > 0.f ? u1 : __expf(u1) - 1.f;
        }
    }
}

// ---------------------------------------------------------------- launch

extern "C" void kernel_launch(void* const* d_in, const int* in_sizes, int n_in,
                              void* d_out, int out_size, void* d_ws, size_t ws_size,
                              hipStream_t stream) {
    (void)in_sizes; (void)n_in; (void)out_size; (void)ws_size;
    const float* feat    = (const float*)d_in[0];
    const int*   adj     = (const int*)d_in[1];
    const float* W_heads = (const float*)d_in[2];
    const float* a_heads = (const float*)d_in[3];
    const float* bnh_g   = (const float*)d_in[4];
    const float* bnh_b   = (const float*)d_in[5];
    const float* bnt_g   = (const float*)d_in[6];
    const float* bnt_b   = (const float*)d_in[7];
    const float* W_sent  = (const float*)d_in[8];
    const float* a_sent  = (const float*)d_in[9];
    const float* bns_g   = (const float*)d_in[10];
    const float* bns_b   = (const float*)d_in[11];
    const float* W_para  = (const float*)d_in[12];
    const float* a_para  = (const float*)d_in[13];
    const float* bnp_g   = (const float*)d_in[14];
    const float* bnp_b   = (const float*)d_in[15];
    const float* W_q     = (const float*)d_in[16];
    const float* a_q     = (const float*)d_in[17];
    const float* bnq_g   = (const float*)d_in[18];
    const float* bnq_b   = (const float*)d_in[19];
    const float* W2      = (const float*)d_in[20];
    float* out = (float*)d_out;
    float* ws  = (float*)d_ws;

    _Float16* h16   = (_Float16*)ws;              // 6,553,600 h = 3,276,800 f
    _Float16* x16h  = (_Float16*)(ws + 3276800);  // 6,553,600 h (head-major [8][25600][32])
    _Float16* W2t48 = (_Float16*)(ws + 6553600);  // 12,288 h = 6,144 f
    _Float16* Bt    = (_Float16*)(ws + 6559744);  // 196,608 h = 98,304 f
    unsigned int* maskw = (unsigned int*)(ws + 6658048);  // 204,800 words
    float* H2p   = ws + 6862848;                  // 1,228,800 f (end ~32.4 MB)

    prep<<<dim3(1793), dim3(256), 0, stream>>>(adj, W_heads, W_sent, W_para, W_q,
                                               a_sent, a_para, a_q, maskw, Bt, W2t48);
    gemm1_mfma<<<dim3(200), dim3(512), 0, stream>>>(feat, Bt, h16);
    attn_heads_mfma<<<dim3(1024), dim3(256), 0, stream>>>(h16, a_heads, maskw,
                                                          bnh_g, bnh_b, bnt_g, bnt_b, x16h);
    gemm2m<<<dim3(400), dim3(256), 0, stream>>>(x16h, W2t48, H2p);
    attn_spq<<<dim3(128, 5), dim3(256), 0, stream>>>(H2p, maskw, bns_g, bns_b,
                                                     bnp_g, bnp_b, bnq_g, bnq_b, W2, out);
}

// Round 17
// 255.761 us; speedup vs baseline: 1.0385x; 1.0385x over previous
//
#include <hip/hip_runtime.h>
#include <hip/hip_bf16.h>
#include <cstdint>

#define BN_SCALEF 0.99999500003749975f  // 1/sqrt(1+1e-5)
#define EXP_SHIFT 4.0f

// Problem constants: B=128, N=200, F=768, H=8, Fo=32, Fh=256

typedef _Float16 half8 __attribute__((ext_vector_type(8)));
typedef _Float16 half4 __attribute__((ext_vector_type(4)));
typedef float floatx4 __attribute__((ext_vector_type(4)));

// ---------------------------------------------------------------- prep: pack_mask + Wcat^T + W2t48 (one launch)  [R5 proven version]

__global__ __launch_bounds__(256) void prep(const int* __restrict__ adj,
                                            const float* __restrict__ W_heads,
                                            const float* __restrict__ Ws_in,
                                            const float* __restrict__ Wp_in,
                                            const float* __restrict__ Wq_in,
                                            const float* __restrict__ a_sent,
                                            const float* __restrict__ a_para,
                                            const float* __restrict__ a_q,
                                            unsigned int* __restrict__ maskw,
                                            _Float16* __restrict__ Bt,
                                            _Float16* __restrict__ W2t48) {
    int blk = blockIdx.x;
    int t = threadIdx.x;
    if (blk < 1600) {
        int w = t >> 6, lane = t & 63;
        for (int task = w; task < 64; task += 4) {
            int r = blk * 16 + (task >> 2);
            int c0 = (task & 3) * 64;
            int j = c0 + lane;
            bool v = (j < 200) && (adj[(size_t)r * 200 + j] > 0);
            unsigned long long m = __ballot(v ? 1 : 0);
            if (lane == 0) {
                maskw[r * 8 + (c0 >> 5)]     = (unsigned int)(m & 0xffffffffULL);
                maskw[r * 8 + (c0 >> 5) + 1] = (unsigned int)(m >> 32);
            }
        }
    } else if (blk < 1792) {
        __shared__ float ld[32][36];
        int blk2 = blk - 1600;          // h = blk2/24, f-tile = blk2%24
        int h = blk2 / 24, f0 = (blk2 % 24) * 32;
        int idx = t * 4;
        int fr = idx >> 5, o0 = idx & 31;
        float4 v = *(const float4*)&W_heads[(size_t)h * 24576 + (size_t)(f0 + fr) * 32 + o0];
        ld[fr][o0] = v.x; ld[fr][o0 + 1] = v.y; ld[fr][o0 + 2] = v.z; ld[fr][o0 + 3] = v.w;
        __syncthreads();
        int o = idx >> 5, fr0 = idx & 31;
        half4 hv;
#pragma unroll
        for (int u = 0; u < 4; ++u) hv[u] = (_Float16)ld[fr0 + u][o];
        *(half4*)&Bt[(size_t)(h * 32 + o) * 768 + f0 + fr0] = hv;
    } else {
        int k = t;  // 256
        for (int c = 0; c < 36; ++c) {
            float v;
            if (c < 2)      v = Ws_in[k * 2 + c];
            else if (c < 4) v = Wp_in[k * 2 + (c - 2)];
            else            v = Wq_in[k * 32 + (c - 4)];
            W2t48[c * 256 + k] = (_Float16)v;
        }
        W2t48[36 * 256 + k] = (_Float16)(Ws_in[k * 2] * a_sent[0] + Ws_in[k * 2 + 1] * a_sent[1]);
        W2t48[37 * 256 + k] = (_Float16)(Ws_in[k * 2] * a_sent[2] + Ws_in[k * 2 + 1] * a_sent[3]);
        W2t48[38 * 256 + k] = (_Float16)(Wp_in[k * 2] * a_para[0] + Wp_in[k * 2 + 1] * a_para[1]);
        W2t48[39 * 256 + k] = (_Float16)(Wp_in[k * 2] * a_para[2] + Wp_in[k * 2 + 1] * a_para[3]);
        float q1 = 0.f, q2 = 0.f;
#pragma unroll
        for (int o = 0; o < 32; ++o) {
            q1 += Wq_in[k * 32 + o] * a_q[o];
            q2 += Wq_in[k * 32 + o] * a_q[32 + o];
        }
        W2t48[40 * 256 + k] = (_Float16)q1;
        W2t48[41 * 256 + k] = (_Float16)q2;
        for (int c = 42; c < 48; ++c) W2t48[c * 256 + k] = (_Float16)0.f;
    }
}

// ---------------------------------------------------------------- GEMM1 v8 (proven 52-53.7): v6 skeleton + dist-2 register prefetch

__global__ __launch_bounds__(512) void gemm1_mfma(const float* __restrict__ A,
                                                  const _Float16* __restrict__ Bt,
                                                  _Float16* __restrict__ h16) {
    __shared__ __align__(16) _Float16 As[128 * 40];   // [row][k], pad 8
    __shared__ __align__(16) _Float16 Bs[256 * 40];   // [col][k]
    int t = threadIdx.x;
    int m0 = blockIdx.x * 128;      // 200 blocks
    int w = t >> 6, lane = t & 63;
    int wr = w >> 2, wc = w & 3;    // 2x4 wave grid; wave tile 64 rows x 64 cols
    int quad = lane >> 4, l16 = lane & 15;

    floatx4 acc[4][4];
#pragma unroll
    for (int i = 0; i < 4; ++i)
#pragma unroll
        for (int j = 0; j < 4; ++j) acc[i][j] = (floatx4){0.f, 0.f, 0.f, 0.f};

    int arow = t >> 2, ako = (t & 3) * 8;      // A: 128 rows x 32 k, two float4/thread
    int bcol = t >> 1, bko = (t & 1) * 16;     // B: 256 cols x 32 k, two uint4/thread
    const float*    Aptr = &A[(size_t)(m0 + arow) * 768 + ako];
    const _Float16* Bptr = &Bt[(size_t)bcol * 768 + bko];

    // regset X holds tiles 0,2,4,.. ; regset Y holds tiles 1,3,5,..
    float4 xa0 = *(const float4*)(Aptr);
    float4 xa1 = *(const float4*)(Aptr + 4);
    uint4  xb0 = *(const uint4*)(Bptr);
    uint4  xb1 = *(const uint4*)(Bptr + 8);
    float4 ya0 = *(const float4*)(Aptr + 32);
    float4 ya1 = *(const float4*)(Aptr + 36);
    uint4  yb0 = *(const uint4*)(Bptr + 32);
    uint4  yb1 = *(const uint4*)(Bptr + 40);

#define GEMM1_BODY(PA0, PA1, PB0, PB1, KNEXT)                                  \
    {                                                                          \
        half4 ah;                                                              \
        ah[0] = (_Float16)PA0.x; ah[1] = (_Float16)PA0.y;                      \
        ah[2] = (_Float16)PA0.z; ah[3] = (_Float16)PA0.w;                      \
        *(half4*)&As[arow * 40 + ako] = ah;                                    \
        ah[0] = (_Float16)PA1.x; ah[1] = (_Float16)PA1.y;                      \
        ah[2] = (_Float16)PA1.z; ah[3] = (_Float16)PA1.w;                      \
        *(half4*)&As[arow * 40 + ako + 4] = ah;                                \
        *(uint4*)&Bs[bcol * 40 + bko]     = PB0;                               \
        *(uint4*)&Bs[bcol * 40 + bko + 8] = PB1;                               \
        __syncthreads();                                                       \
        if ((KNEXT) < 768) {                                                   \
            PA0 = *(const float4*)(Aptr + (KNEXT));                            \
            PA1 = *(const float4*)(Aptr + (KNEXT) + 4);                        \
            PB0 = *(const uint4*)(Bptr + (KNEXT));                             \
            PB1 = *(const uint4*)(Bptr + (KNEXT) + 8);                         \
        }                                                                      \
        half8 af[4], bf[4];                                                    \
        _Pragma("unroll")                                                      \
        for (int rt = 0; rt < 4; ++rt)                                         \
            af[rt] = *(half8*)&As[(wr * 64 + rt * 16 + l16) * 40 + quad * 8];  \
        _Pragma("unroll")                                                      \
        for (int ct = 0; ct < 4; ++ct)                                         \
            bf[ct] = *(half8*)&Bs[(wc * 64 + ct * 16 + l16) * 40 + quad * 8];  \
        _Pragma("unroll")                                                      \
        for (int rt = 0; rt < 4; ++rt)                                         \
            _Pragma("unroll")                                                  \
            for (int ct = 0; ct < 4; ++ct)                                     \
                acc[rt][ct] = __builtin_amdgcn_mfma_f32_16x16x32_f16(af[rt], bf[ct], acc[rt][ct], 0, 0, 0); \
        __syncthreads();                                                       \
    }

    for (int k0 = 0; k0 < 768; k0 += 64) {
        GEMM1_BODY(xa0, xa1, xb0, xb1, k0 + 64)     // tile k0   (dist-2: loads k0+64)
        GEMM1_BODY(ya0, ya1, yb0, yb1, k0 + 96)     // tile k0+32 (dist-2: loads k0+96)
    }
#undef GEMM1_BODY

    int rbase = m0 + wr * 64;
    int cbase = wc * 64;
#pragma unroll
    for (int rt = 0; rt < 4; ++rt)
#pragma unroll
        for (int ct = 0; ct < 4; ++ct) {
            int gc = cbase + ct * 16 + l16;
#pragma unroll
            for (int r = 0; r < 4; ++r) {
                int gr = rbase + rt * 16 + quad * 4 + r;
                h16[(size_t)gr * 256 + gc] = (_Float16)acc[rt][ct][r];
            }
        }
}

// ---------------------------------------------------------------- head attention v4: P built directly in registers (R8 proven)

__global__ __launch_bounds__(256) void attn_heads_mfma(
    const _Float16* __restrict__ h16,
    const float* __restrict__ a_h,
    const unsigned int* __restrict__ maskw,
    const float* __restrict__ bnh_g, const float* __restrict__ bnh_b,
    const float* __restrict__ bnt_g, const float* __restrict__ bnt_b,
    _Float16* __restrict__ x16h) {
    __shared__ __align__(16) _Float16 Bs[32 * 228];   // h^T rows 0..31
    __shared__ __align__(16) _Float16 Bs2[16 * 228];  // row 0 = ones; bytes 512.. = Ms
    __shared__ float s1s[256], s2s[256];
    unsigned int* Ms = (unsigned int*)((char*)Bs2 + 512);   // 200 rows x 8 words = 6400 B
    int hb = blockIdx.x;
    int h = hb >> 7, b = hb & 127;
    int t = threadIdx.x;

    // ---- prologue (single barrier): s1/s2 from global, Bs stage+tail-zero,
    //      Bs2 row 0, mask table
    if (t < 200) {
        const _Float16* hp = &h16[(size_t)(b * 200 + t) * 256 + h * 32];
        half8 v0 = *(const half8*)(hp);
        half8 v1 = *(const half8*)(hp + 8);
        half8 v2 = *(const half8*)(hp + 16);
        half8 v3 = *(const half8*)(hp + 24);
        const float* ab = &a_h[h * 64];
        float acc1 = 0.f, acc2 = 0.f;
#pragma unroll
        for (int o = 0; o < 8; ++o) {
            acc1 += (float)v0[o] * ab[o]      + (float)v1[o] * ab[8 + o]
                  + (float)v2[o] * ab[16 + o] + (float)v3[o] * ab[24 + o];
            acc2 += (float)v0[o] * ab[32 + o] + (float)v1[o] * ab[40 + o]
                  + (float)v2[o] * ab[48 + o] + (float)v3[o] * ab[56 + o];
        }
        s1s[t] = acc1; s2s[t] = acc2;
    } else {
        s1s[t] = 0.f; s2s[t] = 0.f;
    }
    for (int idx = t; idx < 800; idx += 256) {
        int j = idx >> 2, w8 = (idx & 3) * 8;
        half8 v = *(const half8*)&h16[(size_t)(b * 200 + j) * 256 + h * 32 + w8];
#pragma unroll
        for (int u = 0; u < 8; ++u) Bs[(w8 + u) * 228 + j] = v[u];
    }
    if (t < 224) {   // zero Bs cols 200..227, rows 0..27
        int zr = t >> 3, zc = (t & 7) * 4;
        if (zc < 28) {
            half4 z = {(_Float16)0.f, (_Float16)0.f, (_Float16)0.f, (_Float16)0.f};
            *(half4*)&Bs[zr * 228 + 200 + zc] = z;
        }
    }
    if (t >= 224 && t < 256) {   // rows 28..31
        int zr = 28 + ((t - 224) >> 3), zc = ((t - 224) & 7) * 4;
        if (zc < 28) {
            half4 z = {(_Float16)0.f, (_Float16)0.f, (_Float16)0.f, (_Float16)0.f};
            *(half4*)&Bs[zr * 228 + 200 + zc] = z;
        }
    }
    if (t < 228) Bs2[t] = (t < 200) ? (_Float16)1.0f : (_Float16)0.f;
    for (int idx = t; idx < 400; idx += 256)
        *(uint4*)&Ms[idx * 4] = *(const uint4*)&maskw[(size_t)b * 1600 + idx * 4];
    __syncthreads();

    int w = t >> 6, lane = t & 63;
    int l16 = lane & 15, quad = lane >> 4;

    for (int tile = w; tile < 13; tile += 4) {
        int i_base = tile * 16;
        int i = i_base + l16;                 // this lane's P row (may be >=200: masked later)
        float s1v = s1s[i];
        half8 pa[7];
#pragma unroll
        for (int kt = 0; kt < 7; ++kt) {
            unsigned int mw = Ms[i * 8 + kt];
            unsigned int bits = (mw >> (quad * 8)) & 0xffu;
            const float* s2p = &s2s[kt * 32 + quad * 8];
            float4 sa = *(const float4*)s2p;
            float4 sb = *(const float4*)(s2p + 4);
            half8 pv;
#pragma unroll
            for (int u = 0; u < 8; ++u) {
                float s2v = (u < 4) ? ((const float*)&sa)[u] : ((const float*)&sb)[u - 4];
                float e = s1v + s2v;
                e = fmaxf(e, 0.3f * e);
                float p = ((bits >> u) & 1u) ? __expf(e - EXP_SHIFT) : 0.f;
                pv[u] = (_Float16)p;
            }
            pa[kt] = pv;
        }
        floatx4 acc0 = {0.f, 0.f, 0.f, 0.f};
        floatx4 acc1 = {0.f, 0.f, 0.f, 0.f};
        floatx4 acc2 = {0.f, 0.f, 0.f, 0.f};
#pragma unroll
        for (int kt = 0; kt < 7; ++kt) {
            half8 b0 = *(half8*)&Bs[(l16) * 228 + kt * 32 + quad * 8];
            half8 b1 = *(half8*)&Bs[(16 + l16) * 228 + kt * 32 + quad * 8];
            half8 b2 = *(half8*)&Bs2[(l16) * 228 + kt * 32 + quad * 8];
            acc0 = __builtin_amdgcn_mfma_f32_16x16x32_f16(pa[kt], b0, acc0, 0, 0, 0);
            acc1 = __builtin_amdgcn_mfma_f32_16x16x32_f16(pa[kt], b1, acc1, 0, 0, 0);
            acc2 = __builtin_amdgcn_mfma_f32_16x16x32_f16(pa[kt], b2, acc2, 0, 0, 0);
        }
#pragma unroll
        for (int r = 0; r < 4; ++r) {
            int io = i_base + quad * 4 + r;
            float rsum = __shfl(acc2[r], (lane & 48), 64);
            if (io < 200) {
                float inv = 1.f / rsum;
                float g1 = BN_SCALEF * bnh_g[h * 200 + io], c1 = bnh_b[h * 200 + io];
                float g2 = BN_SCALEF * bnt_g[io], c2 = bnt_b[io];
                float v0 = acc0[r] * inv * g1 + c1;
                v0 = v0 > 0.f ? v0 : __expf(v0) - 1.f;
                v0 = v0 * g2 + c2;
                float v1 = acc1[r] * inv * g1 + c1;
                v1 = v1 > 0.f ? v1 : __expf(v1) - 1.f;
                v1 = v1 * g2 + c2;
                size_t base = (size_t)h * 819200 + (size_t)(b * 200 + io) * 32;
                x16h[base + l16]      = (_Float16)v0;
                x16h[base + 16 + l16] = (_Float16)v1;
            }
        }
    }
}

// ---------------------------------------------------------------- GEMM2 via MFMA: H2p[25600][48] = x16h @ W2t48^T

__global__ __launch_bounds__(256) void gemm2m(const _Float16* __restrict__ Xh,
                                              const _Float16* __restrict__ Wt,
                                              float* __restrict__ H2p) {
    __shared__ __align__(16) _Float16 Xs[64 * 264];   // [row][k = h*32+o], pad 8
    __shared__ __align__(16) _Float16 Ws[48 * 264];
    int t = threadIdx.x;
    int m0 = blockIdx.x * 64;       // 400 blocks
    int srow = t >> 2, schunk = (t & 3) * 8;
#pragma unroll
    for (int h = 0; h < 8; ++h) {
        half8 v = *(const half8*)&Xh[(size_t)h * 819200 + (size_t)(m0 + srow) * 32 + schunk];
        *(half8*)&Xs[srow * 264 + h * 32 + schunk] = v;
    }
#pragma unroll
    for (int p = 0; p < 6; ++p) {
        int g = t + 256 * p;                 // 1536 half8 chunks
        int n = g >> 5, ko = (g & 31) * 8;
        *(half8*)&Ws[n * 264 + ko] = *(const half8*)&Wt[(size_t)n * 256 + ko];
    }
    __syncthreads();

    int w = t >> 6, lane = t & 63;
    int l16 = lane & 15, quad = lane >> 4;
    int rbase = w * 16;
    floatx4 acc[3];
#pragma unroll
    for (int c = 0; c < 3; ++c) acc[c] = (floatx4){0.f, 0.f, 0.f, 0.f};
#pragma unroll
    for (int kt = 0; kt < 8; ++kt) {
        half8 af = *(half8*)&Xs[(rbase + l16) * 264 + kt * 32 + quad * 8];
#pragma unroll
        for (int ct = 0; ct < 3; ++ct) {
            half8 bf = *(half8*)&Ws[(ct * 16 + l16) * 264 + kt * 32 + quad * 8];
            acc[ct] = __builtin_amdgcn_mfma_f32_16x16x32_f16(af, bf, acc[ct], 0, 0, 0);
        }
    }
#pragma unroll
    for (int ct = 0; ct < 3; ++ct) {
        int col = ct * 16 + l16;
#pragma unroll
        for (int r = 0; r < 4; ++r) {
            int row = m0 + rbase + quad * 4 + r;
            H2p[(size_t)row * 48 + col] = acc[ct][r];
        }
    }
}

// ---------------------------------------------------------------- sent+para+q attention v3 (R13 proven): 4 row-chunks of 50 (y=0..3) + q (y=4)

__global__ __launch_bounds__(256) void attn_spq(const float* __restrict__ H2p,
                                                const unsigned int* __restrict__ maskw,
                                                const float* __restrict__ bns_g, const float* __restrict__ bns_b,
                                                const float* __restrict__ bnp_g, const float* __restrict__ bnp_b,
                                                const float* __restrict__ bnq_g, const float* __restrict__ bnq_b,
                                                const float* __restrict__ W2, float* __restrict__ out) {
    int b = blockIdx.x;
    int t = threadIdx.x;
    if (blockIdx.y == 4) {
        __shared__ float p_lds[200];
        __shared__ float redd[4];
        __shared__ float red2[256];
        float s1v = H2p[(size_t)(b * 200) * 48 + 40];
        float p = 0.f;
        if (t < 200) {
            unsigned int mw = maskw[(size_t)(b * 200) * 8 + (t >> 5)];
            if ((mw >> (t & 31)) & 1u) {
                float x = s1v + H2p[(size_t)(b * 200 + t) * 48 + 41];
                x = fmaxf(x, 0.3f * x);
                p = __expf(x - EXP_SHIFT);
            }
            p_lds[t] = p;
        }
        float ds = p;
        for (int off = 32; off; off >>= 1) ds += __shfl_xor(ds, off, 64);
        if ((t & 63) == 0) redd[t >> 6] = ds;
        __syncthreads();
        ds = redd[0] + redd[1] + redd[2] + redd[3];
        int o = t & 31, g = t >> 5;
        float acc = 0.f;
        for (int j = g; j < 200; j += 8)
            acc += p_lds[j] * H2p[(size_t)(b * 200 + j) * 48 + 4 + o];
        red2[t] = acc;
        __syncthreads();
        if (t < 32) {
            float s = 0.f;
#pragma unroll
            for (int gg = 0; gg < 8; ++gg) s += red2[gg * 32 + t];
            float qv = (s / ds) * (BN_SCALEF * bnq_g[0]) + bnq_b[0];
            float c0 = qv * W2[t * 2], c1 = qv * W2[t * 2 + 1];
#pragma unroll
            for (int off = 16; off; off >>= 1) {
                c0 += __shfl_xor(c0, off, 64);
                c1 += __shfl_xor(c1, off, 64);
            }
            if (t == 0) {
                out[102400 + b * 2 + 0] = c0 > 0.f ? c0 : __expf(c0) - 1.f;
                out[102400 + b * 2 + 1] = c1 > 0.f ? c1 : __expf(c1) - 1.f;
            }
        }
        return;
    }
    __shared__ float s2s[200], s2p[200];
    __shared__ float s1sA[200], s1pA[200];
    __shared__ __align__(16) float hsp[200 * 4];
    __shared__ __align__(16) unsigned int Msq[400];   // 50 rows x 8 mask words
    int chunk = blockIdx.y;                            // 0..3, rows [chunk*50, chunk*50+50)
    if (t < 200) {
        const float* hr = &H2p[(size_t)(b * 200 + t) * 48];
        float4 hv = *(const float4*)hr;
        *(float4*)&hsp[t * 4] = hv;
        s1sA[t] = hr[36]; s2s[t] = hr[37];
        s1pA[t] = hr[38]; s2p[t] = hr[39];
    }
    for (int idx = t; idx < 100; idx += 256)
        *(uint4*)&Msq[idx * 4] = *(const uint4*)&maskw[((size_t)(b * 200) + chunk * 50) * 8 + idx * 4];
    __syncthreads();
    int w = t >> 6, lane = t & 63;
    for (int it = 0; it < 13; ++it) {
        int lr = it * 4 + w;                 // local row in chunk
        if (lr >= 50) break;
        int i = chunk * 50 + lr;
        float s1sv = s1sA[i];
        float s1pv = s1pA[i];
        float ds = 0.f, dp = 0.f, pa0 = 0.f, pa1 = 0.f, pb0 = 0.f, pb1 = 0.f;
#pragma unroll
        for (int q = 0; q < 4; ++q) {
            int j = lane + 64 * q;
            if (j < 200) {
                unsigned int mw = Msq[lr * 8 + (j >> 5)];
                if ((mw >> (j & 31)) & 1u) {
                    float x1 = s1sv + s2s[j]; x1 = fmaxf(x1, 0.3f * x1);
                    float x2 = s1pv + s2p[j]; x2 = fmaxf(x2, 0.3f * x2);
                    float p1 = __expf(x1 - EXP_SHIFT), p2 = __expf(x2 - EXP_SHIFT);
                    ds += p1; dp += p2;
                    float4 hv = *(float4*)&hsp[j * 4];
                    pa0 += p1 * hv.x; pa1 += p1 * hv.y;
                    pb0 += p2 * hv.z; pb1 += p2 * hv.w;
                }
            }
        }
        for (int off = 32; off; off >>= 1) {
            ds  += __shfl_xor(ds, off, 64);  dp  += __shfl_xor(dp, off, 64);
            pa0 += __shfl_xor(pa0, off, 64); pa1 += __shfl_xor(pa1, off, 64);
            pb0 += __shfl_xor(pb0, off, 64); pb1 += __shfl_xor(pb1, off, 64);
        }
        if (lane == 0) {
            float gs = BN_SCALEF * bns_g[i], bs = bns_b[i];
            float v0 = (pa0 / ds) * gs + bs, v1 = (pa1 / ds) * gs + bs;
            out[(size_t)(b * 200 + i) * 2 + 0] = 1.f / (1.f + __expf(-v0));
            out[(size_t)(b * 200 + i) * 2 + 1] = 1.f / (1.f + __expf(-v1));
            float gp = BN_SCALEF * bnp_g[i], bp = bnp_b[i];
            float u0 = (pb0 / dp) * gp + bp, u1 = (pb1 / dp) * gp + bp;
            out[51200 + (size_t)(b * 200 + i) * 2 + 0] = u0 > 0.f ? u0 : __expf(u0) - 1.f;
            out[51200 + (size_t)(b * 200 + i) * 2 + 1] = u1 > 0.f ? u1 : __expf(u1) - 1.f;
        }
    }
}

// ---------------------------------------------------------------- launch

extern "C" void kernel_launch(void* const* d_in, const int* in_sizes, int n_in,
                              void* d_out, int out_size, void* d_ws, size_t ws_size,
                              hipStream_t stream) {
    (void)in_sizes; (void)n_in; (void)out_size; (void)ws_size;
    const float* feat    = (const float*)d_in[0];
    const int*   adj     = (const int*)d_in[1];
    const float* W_heads = (const float*)d_in[2];
    const float* a_heads = (const float*)d_in[3];
    const float* bnh_g   = (const float*)d_in[4];
    const float* bnh_b   = (const float*)d_in[5];
    const float* bnt_g   = (const float*)d_in[6];
    const float* bnt_b   = (const float*)d_in[7];
    const float* W_sent  = (const float*)d_in[8];
    const float* a_sent  = (const float*)d_in[9];
    const float* bns_g   = (const float*)d_in[10];
    const float* bns_b   = (const float*)d_in[11];
    const float* W_para  = (const float*)d_in[12];
    const float* a_para  = (const float*)d_in[13];
    const float* bnp_g   = (const float*)d_in[14];
    const float* bnp_b   = (const float*)d_in[15];
    const float* W_q     = (const float*)d_in[16];
    const float* a_q     = (const float*)d_in[17];
    const float* bnq_g   = (const float*)d_in[18];
    const float* bnq_b   = (const float*)d_in[19];
    const float* W2      = (const float*)d_in[20];
    float* out = (float*)d_out;
    float* ws  = (float*)d_ws;

    _Float16* h16   = (_Float16*)ws;              // 6,553,600 h = 3,276,800 f
    _Float16* x16h  = (_Float16*)(ws + 3276800);  // 6,553,600 h (head-major [8][25600][32])
    _Float16* W2t48 = (_Float16*)(ws + 6553600);  // 12,288 h = 6,144 f
    _Float16* Bt    = (_Float16*)(ws + 6559744);  // 196,608 h = 98,304 f
    unsigned int* maskw = (unsigned int*)(ws + 6658048);  // 204,800 words
    float* H2p   = ws + 6862848;                  // 1,228,800 f (end ~32.4 MB)

    prep<<<dim3(1793), dim3(256), 0, stream>>>(adj, W_heads, W_sent, W_para, W_q,
                                               a_sent, a_para, a_q, maskw, Bt, W2t48);
    gemm1_mfma<<<dim3(200), dim3(512), 0, stream>>>(feat, Bt, h16);
    attn_heads_mfma<<<dim3(1024), dim3(256), 0, stream>>>(h16, a_heads, maskw,
                                                          bnh_g, bnh_b, bnt_g, bnt_b, x16h);
    gemm2m<<<dim3(400), dim3(256), 0, stream>>>(x16h, W2t48, H2p);
    attn_spq<<<dim3(128, 5), dim3(256), 0, stream>>>(H2p, maskw, bns_g, bns_b,
                                                     bnp_g, bnp_b, bnq_g, bnq_b, W2, out);
}